// Round 10
// baseline (132.135 us; speedup 1.0000x reference)
//
#include <hip/hip_runtime.h>
#include <hip/hip_fp16.h>

#define BB 4
#define HH 128
#define WW 128
#define CC 32
#define OH 120
#define OW 120
#define KT 25
#define OFFC 100
#define FF 64
#define NPX 32
#define NTHREADS 512

// window geometry: rows [oy-2, oy+10] (13), cols [ox0-2, ox0+42] (45)
#define WROWS 13
#define WCOLS 45
#define WUNITS (WROWS * WCOLS * 4)   // 2340 16B-units

typedef __attribute__((ext_vector_type(8))) short    s16x8;
typedef __attribute__((ext_vector_type(8))) _Float16 f16x8;
typedef __attribute__((ext_vector_type(2))) _Float16 h2;
typedef __attribute__((ext_vector_type(4))) float    f32x4;

// d_ws layout (short elements, fp16 bits):
//   WB:  [25 taps][7 n][64 lane][8]   89,600   (offset-conv weights, B-frag)
//   WD:  [4 n][25 taps][64 lane][8]   51,200   (dcn weights, B-frag)
#define WB_ELEMS   (KT * 7 * 64 * 8)
#define WD_ELEMS   (4 * KT * 64 * 8)

__device__ __forceinline__ short f2h(float x) {
    _Float16 h = (_Float16)x;
    return __builtin_bit_cast(short, h);
}
__device__ __forceinline__ float h2f(short x) {
    return (float)__builtin_bit_cast(_Float16, x);
}
__device__ __forceinline__ unsigned pk2(float a, float b) {
    return ((unsigned)(unsigned short)f2h(a)) | (((unsigned)(unsigned short)f2h(b)) << 16);
}

// ---------------------------------------------------------------------------
// Repack: weights only -> MFMA B-fragment layout (f16). 550 blocks, tiny.
// ---------------------------------------------------------------------------
__global__ __launch_bounds__(256) void repack_kernel(
    const float* __restrict__ w_off, const float* __restrict__ w_dcn,
    short* __restrict__ ws)
{
    int idx = blockIdx.x * 256 + threadIdx.x;
    short* WB = ws;
    short* WD = ws + WB_ELEMS;
    if (idx < WB_ELEMS) {
        int j = idx & 7, l = (idx >> 3) & 63;
        int tn = idx >> 9;            // t*7 + n
        int n = tn % 7, t = tn / 7;
        int c = (l >> 4) * 8 + j;
        int oc = n * 16 + (l & 15);
        float v = (oc < OFFC) ? w_off[(t * CC + c) * OFFC + oc] : 0.f;
        WB[idx] = f2h(v);
    } else if (idx < WB_ELEMS + WD_ELEMS) {
        int idx2 = idx - WB_ELEMS;
        int j = idx2 & 7, l = (idx2 >> 3) & 63;
        int nt = idx2 >> 9;           // n*25 + t
        int t = nt % KT, n = nt / KT;
        int c = (l >> 4) * 8 + j;
        int f = n * 16 + (l & 15);
        WD[idx2] = f2h(w_dcn[(t * CC + c) * FF + f]);
    }
}

// window unit index for pixel q (= wr*WCOLS+wc) and channel-quad c
__device__ __forceinline__ int wunit(int q, int c) {
    return q * 4 + (c ^ (q & 3));
}

// ---------------------------------------------------------------------------
// Fused kernel. Block = 32 px of one output row, 512 threads (8 waves).
//  P1: stage 13x45x32 f16 window from fp32 volume (c-XOR swizzled)
//  P2: offset GEMM (waves 0-6, n-tile each, 2 M-tiles) from window -> offtile
//  P3: 1600 (p,t,g) items -> packed pos {y0,x0,inw, h2(wy,wx)}
//  P4: wave=(mt,g,th): per tap build A-frag from window (ds, bank-optimal;
//      global-fp32 fallback if out-of-window), 2 MFMAs (both f-tiles of g).
//  P5: tap-half reduce via LDS (aliases window), store.
// ---------------------------------------------------------------------------
__global__ __launch_bounds__(512, 4) void dcn_fused(
    const float* __restrict__ volume, const short* __restrict__ ws_ro,
    const float* __restrict__ b_off, const float* __restrict__ b_dcn,
    float* __restrict__ out)
{
    __shared__ __align__(16) char smem[56640];
    short*    window  = (short*)smem;             // 37,440 B
    unsigned* pos4    = (unsigned*)(smem + 37440); // 12,800 B: [25][2][32] uint2
    short*    offtile = (short*)(smem + 50240);   //  6,400 B: [32 px][100] f16
    f32x4*    red     = (f32x4*)smem;             //  8,192 B (aliases window, P5)

    const short* WB = ws_ro;
    const short* WD = ws_ro + WB_ELEMS;

    const int tid  = threadIdx.x;
    const int lane = tid & 63;
    const int wv   = tid >> 6;
    const int ox0  = blockIdx.x * NPX;
    const int oy   = blockIdx.y;
    const int b    = blockIdx.z;
    const float* Vb = volume + (size_t)b * (HH * WW * CC);

    // ---- P1: stage window (fp32 -> f16, clamped rows/cols)
    for (int i = tid; i < WUNITS; i += NTHREADS) {
        int c  = i & 3;
        int wc = (i >> 2) % WCOLS;
        int wr = (i >> 2) / WCOLS;
        int gy = oy - 2 + wr;  gy = max(0, min(HH - 1, gy));
        int gx = ox0 - 2 + wc; gx = max(0, min(WW - 1, gx));
        const float* src = Vb + ((size_t)gy * WW + gx) * CC + c * 8;
        float4 q0 = *(const float4*)src;
        float4 q1 = *(const float4*)(src + 4);
        uint4 r;
        r.x = pk2(q0.x, q0.y); r.y = pk2(q0.z, q0.w);
        r.z = pk2(q1.x, q1.y); r.w = pk2(q1.z, q1.w);
        int q = wr * WCOLS + wc;
        *(uint4*)&window[wunit(q, c) * 8] = r;
    }
    __syncthreads();

    // ---- P2: offset GEMM. wave w<7 -> n-tile w, both M-tiles, K=800.
    if (wv < 7) {
        const int pr = lane & 15, cq = lane >> 4;
        f32x4 a0 = (f32x4){0.f, 0.f, 0.f, 0.f};
        f32x4 a1 = (f32x4){0.f, 0.f, 0.f, 0.f};
        for (int fh = 0; fh < 5; ++fh) {
            #pragma unroll
            for (int fw = 0; fw < 5; ++fw) {
                int t = fh * 5 + fw;
                int q0 = (2 * fh + 2) * WCOLS + (pr + 2 * fw + 2);
                int q1 = q0 + 16;
                f16x8 af0 = *(const f16x8*)&window[wunit(q0, cq) * 8];
                f16x8 af1 = *(const f16x8*)&window[wunit(q1, cq) * 8];
                f16x8 bf = *(const f16x8*)&WB[(t * 7 + wv) * 512 + lane * 8];
                a0 = __builtin_amdgcn_mfma_f32_16x16x32_f16(af0, bf, a0, 0, 0, 0);
                a1 = __builtin_amdgcn_mfma_f32_16x16x32_f16(af1, bf, a1, 0, 0, 0);
            }
        }
        int col = lane & 15, q = lane >> 4;
        int oc = wv * 16 + col;
        if (oc < OFFC) {
            float bo = b_off[oc];
            #pragma unroll
            for (int r = 0; r < 4; ++r) {
                offtile[(q * 4 + r) * 100 + oc]      = f2h(a0[r] + bo);
                offtile[(16 + q * 4 + r) * 100 + oc] = f2h(a1[r] + bo);
            }
        }
    }
    __syncthreads();

    // ---- P3: positions -> packed {y0 | x0<<8 | inw<<16, h2(wy,wx)}
    for (int item = tid; item < 1600; item += NTHREADS) {
        int p = item & 31, g = (item >> 5) & 1, t = item >> 6;
        int pe = (ox0 + p < OW) ? p : (OW - 1 - ox0);
        int t5 = t / 5, tm5 = t - t5 * 5;
        float dy = h2f(offtile[pe * 100 + t * 4 + g]);
        float dx = h2f(offtile[pe * 100 + t * 4 + 2 + g]);
        float py = (float)(oy + 2 * t5) + dy;
        float px = (float)(ox0 + pe + 2 * tm5) + dx;
        py = fminf(fmaxf(py, 0.f), 127.f);
        px = fminf(fmaxf(px, 0.f), 127.f);
        float y0f = fminf(floorf(py), 126.f);
        float x0f = fminf(floorf(px), 126.f);
        float wy = py - y0f, wx = px - x0f;
        int y0 = (int)y0f, x0i = (int)x0f;
        int wr = y0 - oy + 2, wc = x0i - ox0 + 2;
        unsigned inw = ((unsigned)wr <= WROWS - 2u && (unsigned)wc <= WCOLS - 2u) ? 1u : 0u;
        int idx = ((t * 2 + g) * 32 + p) * 2;
        pos4[idx]     = (unsigned)y0 | ((unsigned)x0i << 8) | (inw << 16);
        pos4[idx + 1] = pk2(wy, wx);
    }
    __syncthreads();

    // ---- P4: wave = (mt, g, th). Per tap: A-frag from window, 2 MFMAs.
    const int mt = wv & 1;
    const int g_ = (wv >> 1) & 1;
    const int th = wv >> 2;
    const int t0 = th ? 13 : 0, t1 = th ? 25 : 13;
    const int p_ = mt * 16 + (lane & 15);
    const int cq = lane >> 4;
    const short* wd0 = WD + ((g_ * 2 + 0) * KT) * 512 + lane * 8;
    const short* wd1 = WD + ((g_ * 2 + 1) * KT) * 512 + lane * 8;
    f32x4 acc0 = (f32x4){0.f, 0.f, 0.f, 0.f};
    f32x4 acc1 = (f32x4){0.f, 0.f, 0.f, 0.f};
    const h2 oneh = (h2){(_Float16)1.f, (_Float16)1.f};

    for (int t = t0; t < t1; ++t) {
        int idx = ((t * 2 + g_) * 32 + p_) * 2;
        unsigned pc = pos4[idx];
        unsigned pww = pos4[idx + 1];
        int y0 = pc & 0x7f, x0i = (pc >> 8) & 0x7f;

        _Float16 wy = __builtin_bit_cast(h2, pww)[0];
        _Float16 wx = __builtin_bit_cast(h2, pww)[1];
        h2 vwy = (h2){wy, wy}, vwx = (h2){wx, wx};
        h2 iwy = oneh - vwy, iwx = oneh - vwx;
        h2 W00 = iwy * iwx, W01 = iwy * vwx, W10 = vwy * iwx, W11 = vwy * vwx;

        uint4 Au, Bu, Cu, Du;
        if (pc & 0x10000) {
            int q00 = (y0 - oy + 2) * WCOLS + (x0i - ox0 + 2);
            Au = *(const uint4*)&window[wunit(q00, cq) * 8];
            Bu = *(const uint4*)&window[wunit(q00 + 1, cq) * 8];
            Cu = *(const uint4*)&window[wunit(q00 + WCOLS, cq) * 8];
            Du = *(const uint4*)&window[wunit(q00 + WCOLS + 1, cq) * 8];
        } else {
            const float* vs = Vb + ((size_t)y0 * WW + x0i) * CC + cq * 8;
            #define LD8(dst, ptr) { float4 u0 = *(const float4*)(ptr); float4 u1 = *(const float4*)((ptr) + 4); \
                dst.x = pk2(u0.x, u0.y); dst.y = pk2(u0.z, u0.w); dst.z = pk2(u1.x, u1.y); dst.w = pk2(u1.z, u1.w); }
            LD8(Au, vs)
            LD8(Bu, vs + CC)
            LD8(Cu, vs + WW * CC)
            LD8(Du, vs + WW * CC + CC)
            #undef LD8
        }

        uint4 res;
        {
            h2 r0 = __builtin_bit_cast(h2, Au.x) * W00;
            r0 = __builtin_elementwise_fma(__builtin_bit_cast(h2, Bu.x), W01, r0);
            r0 = __builtin_elementwise_fma(__builtin_bit_cast(h2, Cu.x), W10, r0);
            r0 = __builtin_elementwise_fma(__builtin_bit_cast(h2, Du.x), W11, r0);
            res.x = __builtin_bit_cast(unsigned, r0);
            h2 r1 = __builtin_bit_cast(h2, Au.y) * W00;
            r1 = __builtin_elementwise_fma(__builtin_bit_cast(h2, Bu.y), W01, r1);
            r1 = __builtin_elementwise_fma(__builtin_bit_cast(h2, Cu.y), W10, r1);
            r1 = __builtin_elementwise_fma(__builtin_bit_cast(h2, Du.y), W11, r1);
            res.y = __builtin_bit_cast(unsigned, r1);
            h2 r2 = __builtin_bit_cast(h2, Au.z) * W00;
            r2 = __builtin_elementwise_fma(__builtin_bit_cast(h2, Bu.z), W01, r2);
            r2 = __builtin_elementwise_fma(__builtin_bit_cast(h2, Cu.z), W10, r2);
            r2 = __builtin_elementwise_fma(__builtin_bit_cast(h2, Du.z), W11, r2);
            res.z = __builtin_bit_cast(unsigned, r2);
            h2 r3 = __builtin_bit_cast(h2, Au.w) * W00;
            r3 = __builtin_elementwise_fma(__builtin_bit_cast(h2, Bu.w), W01, r3);
            r3 = __builtin_elementwise_fma(__builtin_bit_cast(h2, Cu.w), W10, r3);
            r3 = __builtin_elementwise_fma(__builtin_bit_cast(h2, Du.w), W11, r3);
            res.w = __builtin_bit_cast(unsigned, r3);
        }
        f16x8 af = __builtin_bit_cast(f16x8, res);
        acc0 = __builtin_amdgcn_mfma_f32_16x16x32_f16(af, *(const f16x8*)&wd0[t * 512], acc0, 0, 0, 0);
        acc1 = __builtin_amdgcn_mfma_f32_16x16x32_f16(af, *(const f16x8*)&wd1[t * 512], acc1, 0, 0, 0);
    }
    __syncthreads();   // all window/pos4 reads complete

    // ---- P5: tap-half reduce (red aliases window region) + store
    if (th) {
        int slot = (mt * 2 + g_) * 2;
        red[(slot + 0) * 64 + lane] = acc0;
        red[(slot + 1) * 64 + lane] = acc1;
    }
    __syncthreads();
    if (!th) {
        int slot = (mt * 2 + g_) * 2;
        acc0 += red[(slot + 0) * 64 + lane];
        acc1 += red[(slot + 1) * 64 + lane];
        int col = lane & 15, q = lane >> 4;
        int f0 = (g_ * 2 + 0) * 16 + col;
        int f1 = (g_ * 2 + 1) * 16 + col;
        float bd0 = b_dcn[f0], bd1 = b_dcn[f1];
        long pix0 = ((long)b * OH + oy) * OW + ox0;
        #pragma unroll
        for (int r = 0; r < 4; ++r) {
            int pp = mt * 16 + q * 4 + r;
            if (ox0 + pp < OW) {
                out[(pix0 + pp) * FF + f0] = acc0[r] + bd0;
                out[(pix0 + pp) * FF + f1] = acc1[r] + bd1;
            }
        }
    }
}

extern "C" void kernel_launch(void* const* d_in, const int* in_sizes, int n_in,
                              void* d_out, int out_size, void* d_ws, size_t ws_size,
                              hipStream_t stream) {
    const float* volume = (const float*)d_in[0];
    const float* w_off  = (const float*)d_in[1];
    const float* b_off  = (const float*)d_in[2];
    const float* w_dcn  = (const float*)d_in[3];
    const float* b_dcn  = (const float*)d_in[4];
    float* out = (float*)d_out;
    short* ws  = (short*)d_ws;   // 0.28 MB used (weights only)

    int repack_blocks = (WB_ELEMS + WD_ELEMS + 255) / 256;   // 550
    repack_kernel<<<repack_blocks, 256, 0, stream>>>(w_off, w_dcn, ws);

    dim3 g2((OW + NPX - 1) / NPX, OH, BB);   // 4 x 120 x 4 = 1920 blocks
    dcn_fused<<<g2, NTHREADS, 0, stream>>>(volume, ws, b_off, b_dcn, out);
}